// Round 1
// 294.040 us; speedup vs baseline: 1.0656x; 1.0656x over previous
//
#include <hip/hip_runtime.h>
#include <math.h>

#define G_    64
#define NPG_  1600
#define N_    (G_*NPG_)     // 102400
#define EPG_  51200
#define E_    (G_*EPG_)     // 3276800
#define FIN_  512
#define HOUT_ 512
#define KEEP_ 1280

// ---------------------------------------------------------------------------
// K1: per-graph CSR build: LDS degree hist -> LDS scan -> LDS-cursor scatter.
// Outputs: offs[v], rend[v], dis[v]=rsqrt(deg+1), csr[] (u16 local src idx).
// ---------------------------------------------------------------------------
__global__ __launch_bounds__(1024) void k_build(const int* __restrict__ esrc,
                                                const int* __restrict__ edst,
                                                int* __restrict__ offs,
                                                int* __restrict__ rend,
                                                float* __restrict__ dis,
                                                unsigned short* __restrict__ csr) {
  __shared__ int hist[NPG_];
  __shared__ int part[1024];
  const int g = blockIdx.x, t = threadIdx.x;
  const int eb = g * EPG_, nb = g * NPG_;

  for (int i = t; i < NPG_; i += 1024) hist[i] = 0;
  __syncthreads();
  for (int e = t; e < EPG_; e += 1024) atomicAdd(&hist[edst[eb + e] - nb], 1);
  __syncthreads();

  int c0 = 0, c1 = 0;
  if (t < 800) { c0 = hist[2 * t]; c1 = hist[2 * t + 1]; }
  part[t] = c0 + c1;
  __syncthreads();
  for (int st = 1; st < 1024; st <<= 1) {
    const int tmp = (t >= st) ? part[t - st] : 0;
    __syncthreads();
    part[t] += tmp;
    __syncthreads();
  }
  if (t < 800) {
    const int excl = part[t] - (c0 + c1);
    const int p0 = eb + excl, p1 = p0 + c0;
    offs[nb + 2 * t] = p0;     rend[nb + 2 * t] = p1;
    offs[nb + 2 * t + 1] = p1; rend[nb + 2 * t + 1] = p1 + c1;
    dis[nb + 2 * t] = rsqrtf((float)c0 + 1.0f);
    dis[nb + 2 * t + 1] = rsqrtf((float)c1 + 1.0f);
    hist[2 * t] = p0;          // reuse as cursor
    hist[2 * t + 1] = p1;
  }
  __syncthreads();
  for (int e = t; e < EPG_; e += 1024) {
    const int s = esrc[eb + e];
    const int d = edst[eb + e] - nb;
    const int p = atomicAdd(&hist[d], 1);
    csr[p] = (unsigned short)(s - nb);
  }
}

// ---------------------------------------------------------------------------
// K2: fused full-K GEMV: hd[r] = (x[r] @ W1) * dis[r].  One row per thread,
// 128 independent float4 loads deep in flight; W1 addresses are wave-uniform
// (loop-counter only) -> scalar-cache broadcasts.  Replaces split-K partials
// + k_hsum: saves 59 MB of HBM round-trip and one launch.
// ---------------------------------------------------------------------------
__global__ __launch_bounds__(256) void k_xw1(const float* __restrict__ x,
                                             const float* __restrict__ W1,
                                             const float* __restrict__ dis,
                                             float* __restrict__ hd) {
  const int r = blockIdx.x * 256 + threadIdx.x;   // grid 400
  const float4* xr = reinterpret_cast<const float4*>(x + (size_t)r * FIN_);
  float acc[16];
#pragma unroll
  for (int j = 0; j < 16; ++j) acc[j] = 0.f;
#pragma unroll 8
  for (int k4 = 0; k4 < 128; ++k4) {
    const float4 xv = xr[k4];
    const float* w = W1 + k4 * 64;                // uniform -> scalar cache
#pragma unroll
    for (int j = 0; j < 16; ++j) acc[j] = fmaf(xv.x, w[j], acc[j]);
#pragma unroll
    for (int j = 0; j < 16; ++j) acc[j] = fmaf(xv.y, w[16 + j], acc[j]);
#pragma unroll
    for (int j = 0; j < 16; ++j) acc[j] = fmaf(xv.z, w[32 + j], acc[j]);
#pragma unroll
    for (int j = 0; j < 16; ++j) acc[j] = fmaf(xv.w, w[48 + j], acc[j]);
  }
  const float dd = dis[r];
  float4* pr = reinterpret_cast<float4*>(hd) + (size_t)r * 4;
  pr[0] = make_float4(acc[0] * dd, acc[1] * dd, acc[2] * dd, acc[3] * dd);
  pr[1] = make_float4(acc[4] * dd, acc[5] * dd, acc[6] * dd, acc[7] * dd);
  pr[2] = make_float4(acc[8] * dd, acc[9] * dd, acc[10] * dd, acc[11] * dd);
  pr[3] = make_float4(acc[12] * dd, acc[13] * dd, acc[14] * dd, acc[15] * dd);
}

// ---------------------------------------------------------------------------
// K3: conv1 gather, LDS-staged.  The per-graph hd slice (1600*16*4B=102.4KB)
// fits in the 160KB LDS: stage once (coalesced float4), gather from LDS
// instead of 64B random L2 loads (which were latency-bound at 4-in-flight).
// 4 blocks/graph x 1024 thr = 256 blocks = 1 LDS-limited block per CU.
// ---------------------------------------------------------------------------
__global__ __launch_bounds__(1024) void k_conv1l(
    const unsigned short* __restrict__ csr, const int* __restrict__ offs,
    const int* __restrict__ rend, const float* __restrict__ hd,
    const float* __restrict__ dis, const float* __restrict__ b1,
    const float* __restrict__ Wrel, const float* __restrict__ Wroot,
    float* __restrict__ h1, float* __restrict__ rarr, float* __restrict__ tarr) {
  __shared__ float hds[NPG_ * 16];                // 102,400 B
  const int g = blockIdx.x >> 2, q = blockIdx.x & 3;
  const int nb = g * NPG_;
  const int t = threadIdx.x;
  {
    const float4* src = reinterpret_cast<const float4*>(hd + (size_t)nb * 16);
    float4* dst = reinterpret_cast<float4*>(hds);
    for (int i = t; i < NPG_ * 4; i += 1024) dst[i] = src[i];
  }
  __syncthreads();
  const int c = t & 15;
  const float bb = b1[c], wr = Wrel[c], wo = Wroot[c];
  const int vend = q * 400 + 400;
  for (int vl = q * 400 + (t >> 4); vl < vend; vl += 64) {
    const int v = nb + vl;
    const int rs = offs[v], re = rend[v];
    float acc = 0.f;
    int k = rs;
    for (; k + 4 <= re; k += 4) {
      const int s0 = csr[k], s1 = csr[k + 1];
      const int s2 = csr[k + 2], s3 = csr[k + 3];
      acc += hds[s0 * 16 + c] + hds[s1 * 16 + c];
      acc += hds[s2 * 16 + c] + hds[s3 * 16 + c];
    }
    for (; k < re; ++k) acc += hds[csr[k] * 16 + c];
    const float dd = dis[v];
    float val = fmaf(acc + hds[vl * 16 + c], dd, bb);
    val = fmaxf(val, 0.f);
    h1[(size_t)v * 16 + c] = val;
    float r = val * wr;
    float tt = val * wo;
#pragma unroll
    for (int m = 1; m < 16; m <<= 1) {
      r += __shfl_xor(r, m);
      tt += __shfl_xor(tt, m);
    }
    if (c == 0) { rarr[v] = r; tarr[v] = tt; }
  }
}

// ---------------------------------------------------------------------------
// K4: per-graph fused score + radix-select top-K (stable, index tie-break) +
// filtered degree + h1w = h1*score*dis2 + out zeroing.  64 blocks x 1024.
// ---------------------------------------------------------------------------
__global__ __launch_bounds__(1024) void k_scoretopk(
    const unsigned short* __restrict__ csr, const int* __restrict__ offs,
    const int* __restrict__ rend, const float* __restrict__ rarr,
    const float* __restrict__ tarr, const float* __restrict__ brel,
    const float* __restrict__ h1, int* __restrict__ kept,
    float* __restrict__ dis2, float* __restrict__ h1w,
    float* __restrict__ out) {
  __shared__ float rar[NPG_];
  __shared__ float sar[NPG_];       // tarr, then score
  __shared__ int   ofs[NPG_];
  __shared__ int   ren[NPG_];
  __shared__ unsigned uu[NPG_];     // monotone keys
  __shared__ int   kp[NPG_];
  __shared__ float wv[NPG_];
  __shared__ int   hist[256];
  __shared__ int   part[1024];
  __shared__ int   scal[2];         // lo, rem

  const int g = blockIdx.x, t = threadIdx.x;
  const int nb = g * NPG_;

  // P0: stage
  for (int i = t; i < NPG_; i += 1024) {
    rar[i] = rarr[nb + i];
    sar[i] = tarr[nb + i];
    ofs[i] = offs[nb + i];
    ren[i] = rend[nb + i];
  }
  if (t == 0) { scal[0] = 0; scal[1] = KEEP_; }
  __syncthreads();

  // P1: score = tanh(sum rar[neighbors] + brel + tarr)
  const float br = brel[0];
  for (int v = t; v < NPG_; v += 1024) {
    const int rs = ofs[v], re = ren[v];
    float sum = 0.f;
    int k = rs;
    for (; k + 4 <= re; k += 4) {
      sum += rar[csr[k]] + rar[csr[k + 1]];
      sum += rar[csr[k + 2]] + rar[csr[k + 3]];
    }
    for (; k < re; ++k) sum += rar[csr[k]];
    const float s = tanhf(sum + br + sar[v]);
    sar[v] = s;
    const unsigned ub = __float_as_uint(s);
    uu[v] = (ub & 0x80000000u) ? ~ub : (ub | 0x80000000u);
  }
  __syncthreads();

  // P2: radix select (4 passes of 8 bits, MSB first)
  const unsigned maskTab[4] = {0u, 0xFF000000u, 0xFFFF0000u, 0xFFFFFF00u};
  const int shTab[4] = {24, 16, 8, 0};
  for (int pass = 0; pass < 4; ++pass) {
    const unsigned lo = (unsigned)scal[0];
    const int remc = scal[1];
    const unsigned msk = maskTab[pass];
    const int sh = shTab[pass];
    if (t < 256) hist[t] = 0;
    __syncthreads();
    for (int v = t; v < NPG_; v += 1024) {
      const unsigned u = uu[v];
      if (((u ^ lo) & msk) == 0) atomicAdd(&hist[(u >> sh) & 255], 1);
    }
    __syncthreads();
    for (int st = 1; st < 256; st <<= 1) {   // suffix-sum
      int tmp = 0;
      if (t < 256) tmp = (t + st < 256) ? hist[t + st] : 0;
      __syncthreads();
      if (t < 256) hist[t] += tmp;
      __syncthreads();
    }
    if (t < 256) {
      const int sb = hist[t], sb1 = (t < 255) ? hist[t + 1] : 0;
      if (sb >= remc && sb1 < remc) {        // unique boundary bin
        scal[0] = (int)(lo | ((unsigned)t << sh));
        scal[1] = remc - sb1;
      }
    }
    __syncthreads();
  }
  const unsigned T = (unsigned)scal[0];
  const int remT = scal[1];

  // tie-break by index: keep first remT nodes with key == T
  const int i0 = 2 * t, i1 = 2 * t + 1;
  int f0 = 0, f1 = 0;
  if (i0 < NPG_) f0 = (uu[i0] == T);
  if (i1 < NPG_) f1 = (uu[i1] == T);
  part[t] = f0 + f1;
  __syncthreads();
  for (int st = 1; st < 1024; st <<= 1) {
    const int tmp = (t >= st) ? part[t - st] : 0;
    __syncthreads();
    part[t] += tmp;
    __syncthreads();
  }
  const int excl = part[t] - (f0 + f1);
  if (i0 < NPG_) kp[i0] = (uu[i0] > T) || (f0 && excl < remT);
  if (i1 < NPG_) kp[i1] = (uu[i1] > T) || (f1 && (excl + f0) < remT);
  __syncthreads();
  for (int v = t; v < NPG_; v += 1024) kept[nb + v] = kp[v];

  // P3: filtered degree -> dis2, wv = score * dis2 (0 for dropped)
  for (int v = t; v < NPG_; v += 1024) {
    float w = 0.f;
    if (kp[v]) {
      const int rs = ofs[v], re = ren[v];
      int c2 = 0, k = rs;
      for (; k + 4 <= re; k += 4) {
        c2 += kp[csr[k]] + kp[csr[k + 1]];
        c2 += kp[csr[k + 2]] + kp[csr[k + 3]];
      }
      for (; k < re; ++k) c2 += kp[csr[k]];
      const float d2 = rsqrtf((float)c2 + 1.0f);
      dis2[nb + v] = d2;
      w = sar[v] * d2;
    }
    wv[v] = w;
  }
  // zero the output slice for this graph
  if (t < HOUT_) out[g * HOUT_ + t] = 0.f;
  __syncthreads();

  // P4: h1w = h1 * wv[v]
  for (int i = t; i < NPG_ * 16; i += 1024)
    h1w[(size_t)nb * 16 + i] = h1[(size_t)nb * 16 + i] * wv[i >> 4];
}

// ---------------------------------------------------------------------------
// K5: conv2 gather, LDS-staged (same structure as K3).  Dropped nodes have
// h1w == 0 so they contribute nothing; y16 written for kept v only.
// ---------------------------------------------------------------------------
__global__ __launch_bounds__(1024) void k_conv2l(
    const unsigned short* __restrict__ csr, const int* __restrict__ offs,
    const int* __restrict__ rend, const float* __restrict__ h1w,
    const int* __restrict__ kept, const float* __restrict__ dis2,
    float* __restrict__ y16) {
  __shared__ float hds[NPG_ * 16];                // 102,400 B
  const int g = blockIdx.x >> 2, q = blockIdx.x & 3;
  const int nb = g * NPG_;
  const int t = threadIdx.x;
  {
    const float4* src = reinterpret_cast<const float4*>(h1w + (size_t)nb * 16);
    float4* dst = reinterpret_cast<float4*>(hds);
    for (int i = t; i < NPG_ * 4; i += 1024) dst[i] = src[i];
  }
  __syncthreads();
  const int c = t & 15;
  const int vend = q * 400 + 400;
  for (int vl = q * 400 + (t >> 4); vl < vend; vl += 64) {
    const int v = nb + vl;
    if (!kept[v]) continue;                       // uniform per 16-group
    const int rs = offs[v], re = rend[v];
    float acc = 0.f;
    int k = rs;
    for (; k + 4 <= re; k += 4) {
      const int s0 = csr[k], s1 = csr[k + 1];
      const int s2 = csr[k + 2], s3 = csr[k + 3];
      acc += hds[s0 * 16 + c] + hds[s1 * 16 + c];
      acc += hds[s2 * 16 + c] + hds[s3 * 16 + c];
    }
    for (; k < re; ++k) acc += hds[csr[k] * 16 + c];
    acc += hds[vl * 16 + c];                      // self loop
    y16[(size_t)v * 16 + c] = acc * dis2[v];
  }
}

// ---------------------------------------------------------------------------
// K6: out[g] += relu(y16[v]@W2 + b2)/K  fused GEMM+ReLU+mean-pool.
// ---------------------------------------------------------------------------
__global__ __launch_bounds__(256, 1) void k_gemm2pool(const float* __restrict__ y16,
                                                      const int* __restrict__ kept,
                                                      const float* __restrict__ W2,
                                                      const float* __restrict__ b2,
                                                      float* __restrict__ out) {
  __shared__ float red[256];
  const int blk = blockIdx.x;                     // grid 2048
  const int g = blk >> 5;
  const int sub = blk & 31;
  const int jbase = (sub & 1) * 256;
  const int nstart = g * NPG_ + (sub >> 1) * 100;
  const int tid = threadIdx.x;
  const int wave = tid >> 6, lane = tid & 63;

  float w[16][4];
#pragma unroll
  for (int k = 0; k < 16; ++k)
#pragma unroll
    for (int c = 0; c < 4; ++c)
      w[k][c] = W2[k * HOUT_ + jbase + lane + c * 64];
  float b2r[4];
#pragma unroll
  for (int c = 0; c < 4; ++c) b2r[c] = b2[jbase + lane + c * 64];

  float acc[4] = {0.f, 0.f, 0.f, 0.f};
  for (int i = wave; i < 100; i += 4) {
    const int v = nstart + i;
    if (!kept[v]) continue;                       // wave-uniform
    const float4* yp = reinterpret_cast<const float4*>(y16 + (size_t)v * 16);
    float4 q0 = yp[0], q1 = yp[1], q2 = yp[2], q3 = yp[3];
    const float yv[16] = {q0.x, q0.y, q0.z, q0.w, q1.x, q1.y, q1.z, q1.w,
                          q2.x, q2.y, q2.z, q2.w, q3.x, q3.y, q3.z, q3.w};
    float z[4] = {b2r[0], b2r[1], b2r[2], b2r[3]};
#pragma unroll
    for (int k = 0; k < 16; ++k)
#pragma unroll
      for (int c = 0; c < 4; ++c)
        z[c] = fmaf(yv[k], w[k][c], z[c]);
#pragma unroll
    for (int c = 0; c < 4; ++c) acc[c] += fmaxf(z[c], 0.f);
  }

  red[tid] = 0.f;
  __syncthreads();
#pragma unroll
  for (int c = 0; c < 4; ++c) atomicAdd(&red[lane + 64 * c], acc[c]);
  __syncthreads();
  atomicAdd(&out[g * HOUT_ + jbase + tid], red[tid] * (1.0f / (float)KEEP_));
}

// ---------------------------------------------------------------------------
extern "C" void kernel_launch(void* const* d_in, const int* in_sizes, int n_in,
                              void* d_out, int out_size, void* d_ws, size_t ws_size,
                              hipStream_t stream) {
  (void)in_sizes; (void)n_in; (void)out_size; (void)ws_size;
  const float* x     = (const float*)d_in[0];
  const int*   ei    = (const int*)  d_in[1];
  const float* W1    = (const float*)d_in[3];
  const float* b1    = (const float*)d_in[4];
  const float* Wrel  = (const float*)d_in[5];
  const float* brel  = (const float*)d_in[6];
  const float* Wroot = (const float*)d_in[7];
  const float* W2    = (const float*)d_in[8];
  const float* b2    = (const float*)d_in[9];
  const int* esrc = ei;
  const int* edst = ei + E_;

  // slab quarters: hd / h1 / h1w / y16 (no split-K partials anymore).
  char* ws = (char*)d_ws;
  float*          hd    = (float*)(ws);                    // q0: 6,553,600 B
  float*          h1    = (float*)(ws + 6553600);          // q1
  float*          h1w   = (float*)(ws + 13107200);         // q2
  float*          y16   = (float*)(ws + 19660800);         // q3
  unsigned short* csr   = (unsigned short*)(ws + 26214400);// 6,553,600 B
  int*            offs  = (int*)(ws + 32768000);
  int*            rendp = (int*)(ws + 33177600);
  float*          dis   = (float*)(ws + 33587200);
  int*            kept  = (int*)(ws + 33996800);
  float*          rarr  = (float*)(ws + 34406400);
  float*          tarr  = (float*)(ws + 34816000);
  float*          dis2  = (float*)(ws + 35225600);
  float*          out   = (float*)d_out;

  hipLaunchKernelGGL(k_build,     dim3(G_),    dim3(1024), 0, stream,
                     esrc, edst, offs, rendp, dis, csr);
  hipLaunchKernelGGL(k_xw1,       dim3(400),   dim3(256),  0, stream,
                     x, W1, dis, hd);
  hipLaunchKernelGGL(k_conv1l,    dim3(256),   dim3(1024), 0, stream,
                     csr, offs, rendp, hd, dis, b1, Wrel, Wroot, h1, rarr, tarr);
  hipLaunchKernelGGL(k_scoretopk, dim3(G_),    dim3(1024), 0, stream,
                     csr, offs, rendp, rarr, tarr, brel, h1, kept, dis2, h1w, out);
  hipLaunchKernelGGL(k_conv2l,    dim3(256),   dim3(1024), 0, stream,
                     csr, offs, rendp, h1w, kept, dis2, y16);
  hipLaunchKernelGGL(k_gemm2pool, dim3(2048),  dim3(256),  0, stream,
                     y16, kept, W2, b2, out);
}

// Round 2
// 260.878 us; speedup vs baseline: 1.2011x; 1.1271x over previous
//
#include <hip/hip_runtime.h>
#include <math.h>

#define G_    64
#define NPG_  1600
#define N_    (G_*NPG_)     // 102400
#define EPG_  51200
#define E_    (G_*EPG_)     // 3276800
#define FIN_  512
#define HOUT_ 512
#define KEEP_ 1280

// ---------------------------------------------------------------------------
// K1: per-graph CSR build.  LDS degree hist -> shuffle scan -> LDS-cursor
// scatter INTO LDS (csrs), then coalesced uint4 copy-out.  Avoids 51200
// random 2B global stores per block (64 L2 transactions per wave-store).
// LDS: 102400 (csrs) + 6400 (hist) + 64 = 108.9 KB.
// ---------------------------------------------------------------------------
__global__ __launch_bounds__(1024) void k_build(const int* __restrict__ esrc,
                                                const int* __restrict__ edst,
                                                int* __restrict__ offs,
                                                int* __restrict__ rend,
                                                float* __restrict__ dis,
                                                unsigned short* __restrict__ csr) {
  __shared__ __align__(16) unsigned short csrs[EPG_];   // 102,400 B
  __shared__ int hist[NPG_];                            // 6,400 B
  __shared__ int wsum[16];
  const int g = blockIdx.x, t = threadIdx.x;
  const int lane = t & 63, wid = t >> 6;
  const int eb = g * EPG_, nb = g * NPG_;

  for (int i = t; i < NPG_; i += 1024) hist[i] = 0;
  __syncthreads();
  for (int e = t; e < EPG_; e += 1024) atomicAdd(&hist[edst[eb + e] - nb], 1);
  __syncthreads();

  int c0 = 0, c1 = 0;
  if (t < 800) { c0 = hist[2 * t]; c1 = hist[2 * t + 1]; }
  const int val = c0 + c1;
  int incl = val;
#pragma unroll
  for (int m = 1; m < 64; m <<= 1) {
    const int u = __shfl_up(incl, m);
    if (lane >= m) incl += u;
  }
  if (lane == 63) wsum[wid] = incl;
  __syncthreads();
  int woff = 0;
  for (int w2 = 0; w2 < wid; ++w2) woff += wsum[w2];
  incl += woff;
  if (t < 800) {
    const int excl = incl - val;          // LOCAL edge offset
    const int p0 = excl, p1 = p0 + c0;
    offs[nb + 2 * t] = eb + p0;     rend[nb + 2 * t] = eb + p1;
    offs[nb + 2 * t + 1] = eb + p1; rend[nb + 2 * t + 1] = eb + p1 + c1;
    dis[nb + 2 * t] = rsqrtf((float)c0 + 1.0f);
    dis[nb + 2 * t + 1] = rsqrtf((float)c1 + 1.0f);
    hist[2 * t] = p0;          // reuse as LOCAL cursor
    hist[2 * t + 1] = p1;
  }
  __syncthreads();
  for (int e = t; e < EPG_; e += 1024) {
    const int s = esrc[eb + e];
    const int d = edst[eb + e] - nb;
    const int p = atomicAdd(&hist[d], 1);
    csrs[p] = (unsigned short)(s - nb);
  }
  __syncthreads();
  // coalesced copy-out: 6400 x uint4 (8 u16 each)
  const uint4* s4 = reinterpret_cast<const uint4*>(csrs);
  uint4* d4 = reinterpret_cast<uint4*>(csr + eb);
  for (int i = t; i < EPG_ / 8; i += 1024) d4[i] = s4[i];
}

// ---------------------------------------------------------------------------
// K2: hd[r] = (x[r] @ W1) * dis[r], LDS-tiled.  Staging loads are full-line
// coalesced (16 consecutive float4 per 16-lane group); compute reads each
// thread's own row from LDS (pad 68 floats -> conflict-minimal b128).
// Old version read per-lane rows at 2KB stride: 64 lines/instruction, 16B
// used per 64B line -> up to 4x HBM fetch amplification if MSHRs don't merge.
// ---------------------------------------------------------------------------
#define XW_ROWS 128
#define XW_KCH  64
__global__ __launch_bounds__(128) void k_xw1(const float* __restrict__ x,
                                             const float* __restrict__ W1,
                                             const float* __restrict__ dis,
                                             float* __restrict__ hd) {
  __shared__ float xt[XW_ROWS][XW_KCH + 4];       // 34,816 B, row stride 68
  const int t = threadIdx.x;
  const int r0 = blockIdx.x * XW_ROWS;            // grid 800
  float acc[16];
#pragma unroll
  for (int j = 0; j < 16; ++j) acc[j] = 0.f;
  const float4* xg = reinterpret_cast<const float4*>(x);
  for (int tile = 0; tile < FIN_ / XW_KCH; ++tile) {
    __syncthreads();                              // previous tile fully read
    for (int i = t; i < XW_ROWS * 16; i += 128) {
      const int rr = i >> 4, c4 = i & 15;
      const float4 v = xg[(size_t)(r0 + rr) * 128 + tile * 16 + c4];
      *reinterpret_cast<float4*>(&xt[rr][c4 * 4]) = v;
    }
    __syncthreads();
    const float* wp = W1 + tile * XW_KCH * 16;
#pragma unroll
    for (int k4 = 0; k4 < 16; ++k4) {
      const float4 xv = *reinterpret_cast<const float4*>(&xt[t][k4 * 4]);
      const float* w = wp + k4 * 64;              // uniform -> scalar cache
#pragma unroll
      for (int j = 0; j < 16; ++j) acc[j] = fmaf(xv.x, w[j], acc[j]);
#pragma unroll
      for (int j = 0; j < 16; ++j) acc[j] = fmaf(xv.y, w[16 + j], acc[j]);
#pragma unroll
      for (int j = 0; j < 16; ++j) acc[j] = fmaf(xv.z, w[32 + j], acc[j]);
#pragma unroll
      for (int j = 0; j < 16; ++j) acc[j] = fmaf(xv.w, w[48 + j], acc[j]);
    }
  }
  const int r = r0 + t;
  const float dd = dis[r];
  float4* pr = reinterpret_cast<float4*>(hd) + (size_t)r * 4;
  pr[0] = make_float4(acc[0] * dd, acc[1] * dd, acc[2] * dd, acc[3] * dd);
  pr[1] = make_float4(acc[4] * dd, acc[5] * dd, acc[6] * dd, acc[7] * dd);
  pr[2] = make_float4(acc[8] * dd, acc[9] * dd, acc[10] * dd, acc[11] * dd);
  pr[3] = make_float4(acc[12] * dd, acc[13] * dd, acc[14] * dd, acc[15] * dd);
}

// ---------------------------------------------------------------------------
// K3: conv1 gather, LDS-staged (per-graph hd slice = 102.4 KB in LDS).
// ---------------------------------------------------------------------------
__global__ __launch_bounds__(1024) void k_conv1l(
    const unsigned short* __restrict__ csr, const int* __restrict__ offs,
    const int* __restrict__ rend, const float* __restrict__ hd,
    const float* __restrict__ dis, const float* __restrict__ b1,
    const float* __restrict__ Wrel, const float* __restrict__ Wroot,
    float* __restrict__ h1, float* __restrict__ rarr, float* __restrict__ tarr) {
  __shared__ float hds[NPG_ * 16];                // 102,400 B
  const int g = blockIdx.x >> 2, q = blockIdx.x & 3;
  const int nb = g * NPG_;
  const int t = threadIdx.x;
  {
    const float4* src = reinterpret_cast<const float4*>(hd + (size_t)nb * 16);
    float4* dst = reinterpret_cast<float4*>(hds);
    for (int i = t; i < NPG_ * 4; i += 1024) dst[i] = src[i];
  }
  __syncthreads();
  const int c = t & 15;
  const float bb = b1[c], wr = Wrel[c], wo = Wroot[c];
  const int vend = q * 400 + 400;
  for (int vl = q * 400 + (t >> 4); vl < vend; vl += 64) {
    const int v = nb + vl;
    const int rs = offs[v], re = rend[v];
    float acc = 0.f;
    int k = rs;
    for (; k + 4 <= re; k += 4) {
      const int s0 = csr[k], s1 = csr[k + 1];
      const int s2 = csr[k + 2], s3 = csr[k + 3];
      acc += hds[s0 * 16 + c] + hds[s1 * 16 + c];
      acc += hds[s2 * 16 + c] + hds[s3 * 16 + c];
    }
    for (; k < re; ++k) acc += hds[csr[k] * 16 + c];
    const float dd = dis[v];
    float val = fmaf(acc + hds[vl * 16 + c], dd, bb);
    val = fmaxf(val, 0.f);
    h1[(size_t)v * 16 + c] = val;
    float r = val * wr;
    float tt = val * wo;
#pragma unroll
    for (int m = 1; m < 16; m <<= 1) {
      r += __shfl_xor(r, m);
      tt += __shfl_xor(tt, m);
    }
    if (c == 0) { rarr[v] = r; tarr[v] = tt; }
  }
}

// ---------------------------------------------------------------------------
// K4: per-graph fused score + radix-select top-K + filtered degree + h1w.
// Scans are shuffle-based (2 barriers each instead of 16-20 ladder barriers).
// ---------------------------------------------------------------------------
__global__ __launch_bounds__(1024) void k_scoretopk(
    const unsigned short* __restrict__ csr, const int* __restrict__ offs,
    const int* __restrict__ rend, const float* __restrict__ rarr,
    const float* __restrict__ tarr, const float* __restrict__ brel,
    const float* __restrict__ h1, int* __restrict__ kept,
    float* __restrict__ dis2, float* __restrict__ h1w,
    float* __restrict__ out) {
  __shared__ float rar[NPG_];
  __shared__ float sar[NPG_];       // tarr, then score
  __shared__ int   ofs[NPG_];
  __shared__ int   ren[NPG_];
  __shared__ unsigned uu[NPG_];     // monotone keys
  __shared__ int   kp[NPG_];
  __shared__ float wv[NPG_];
  __shared__ int   hist[256];
  __shared__ int   part[16];        // per-wave scan sums
  __shared__ int   scal[2];         // lo, rem

  const int g = blockIdx.x, t = threadIdx.x;
  const int lane = t & 63, wid = t >> 6;
  const int nb = g * NPG_;

  // P0: stage
  for (int i = t; i < NPG_; i += 1024) {
    rar[i] = rarr[nb + i];
    sar[i] = tarr[nb + i];
    ofs[i] = offs[nb + i];
    ren[i] = rend[nb + i];
  }
  if (t == 0) { scal[0] = 0; scal[1] = KEEP_; }
  __syncthreads();

  // P1: score = tanh(sum rar[neighbors] + brel + tarr)
  const float br = brel[0];
  for (int v = t; v < NPG_; v += 1024) {
    const int rs = ofs[v], re = ren[v];
    float sum = 0.f;
    int k = rs;
    for (; k + 4 <= re; k += 4) {
      sum += rar[csr[k]] + rar[csr[k + 1]];
      sum += rar[csr[k + 2]] + rar[csr[k + 3]];
    }
    for (; k < re; ++k) sum += rar[csr[k]];
    const float s = tanhf(sum + br + sar[v]);
    sar[v] = s;
    const unsigned ub = __float_as_uint(s);
    uu[v] = (ub & 0x80000000u) ? ~ub : (ub | 0x80000000u);
  }
  __syncthreads();

  // P2: radix select (4 passes of 8 bits, MSB first)
  const unsigned maskTab[4] = {0u, 0xFF000000u, 0xFFFF0000u, 0xFFFFFF00u};
  const int shTab[4] = {24, 16, 8, 0};
  for (int pass = 0; pass < 4; ++pass) {
    const unsigned lo = (unsigned)scal[0];
    const int remc = scal[1];
    const unsigned msk = maskTab[pass];
    const int sh = shTab[pass];
    if (t < 256) hist[t] = 0;
    __syncthreads();
    for (int v = t; v < NPG_; v += 1024) {
      const unsigned u = uu[v];
      if (((u ^ lo) & msk) == 0) atomicAdd(&hist[(u >> sh) & 255], 1);
    }
    __syncthreads();
    int hv = 0;
    if (t < 256) hv = hist[t];
    int incl = hv;
#pragma unroll
    for (int m = 1; m < 64; m <<= 1) {
      const int u2 = __shfl_up(incl, m);
      if (lane >= m) incl += u2;
    }
    if (t < 256 && lane == 63) part[wid] = incl;  // waves 0..3
    __syncthreads();
    if (t < 256) {
      int woff = 0;
      for (int w2 = 0; w2 < wid; ++w2) woff += part[w2];
      const int tot = part[0] + part[1] + part[2] + part[3];
      const int sb = tot - (incl + woff) + hv;    // suffix sum from bin t
      const int sb1 = sb - hv;                    // suffix sum from bin t+1
      if (sb >= remc && sb1 < remc) {             // unique boundary bin
        scal[0] = (int)(lo | ((unsigned)t << sh));
        scal[1] = remc - sb1;
      }
    }
    __syncthreads();
  }
  const unsigned T = (unsigned)scal[0];
  const int remT = scal[1];

  // tie-break by index: keep first remT nodes with key == T (shuffle scan)
  const int i0 = 2 * t, i1 = 2 * t + 1;
  int f0 = 0, f1 = 0;
  if (i0 < NPG_) f0 = (uu[i0] == T);
  if (i1 < NPG_) f1 = (uu[i1] == T);
  int incl2 = f0 + f1;
#pragma unroll
  for (int m = 1; m < 64; m <<= 1) {
    const int u2 = __shfl_up(incl2, m);
    if (lane >= m) incl2 += u2;
  }
  if (lane == 63) part[wid] = incl2;
  __syncthreads();
  int woff2 = 0;
  for (int w2 = 0; w2 < wid; ++w2) woff2 += part[w2];
  const int excl = incl2 + woff2 - (f0 + f1);
  if (i0 < NPG_) kp[i0] = (uu[i0] > T) || (f0 && excl < remT);
  if (i1 < NPG_) kp[i1] = (uu[i1] > T) || (f1 && (excl + f0) < remT);
  __syncthreads();
  for (int v = t; v < NPG_; v += 1024) kept[nb + v] = kp[v];

  // P3: filtered degree -> dis2, wv = score * dis2 (0 for dropped)
  for (int v = t; v < NPG_; v += 1024) {
    float w = 0.f;
    if (kp[v]) {
      const int rs = ofs[v], re = ren[v];
      int c2 = 0, k = rs;
      for (; k + 4 <= re; k += 4) {
        c2 += kp[csr[k]] + kp[csr[k + 1]];
        c2 += kp[csr[k + 2]] + kp[csr[k + 3]];
      }
      for (; k < re; ++k) c2 += kp[csr[k]];
      const float d2 = rsqrtf((float)c2 + 1.0f);
      dis2[nb + v] = d2;
      w = sar[v] * d2;
    }
    wv[v] = w;
  }
  // zero the output slice for this graph
  if (t < HOUT_) out[g * HOUT_ + t] = 0.f;
  __syncthreads();

  // P4: h1w = h1 * wv[v]
  for (int i = t; i < NPG_ * 16; i += 1024)
    h1w[(size_t)nb * 16 + i] = h1[(size_t)nb * 16 + i] * wv[i >> 4];
}

// ---------------------------------------------------------------------------
// K5: conv2 gather, LDS-staged (same structure as K3).
// ---------------------------------------------------------------------------
__global__ __launch_bounds__(1024) void k_conv2l(
    const unsigned short* __restrict__ csr, const int* __restrict__ offs,
    const int* __restrict__ rend, const float* __restrict__ h1w,
    const int* __restrict__ kept, const float* __restrict__ dis2,
    float* __restrict__ y16) {
  __shared__ float hds[NPG_ * 16];                // 102,400 B
  const int g = blockIdx.x >> 2, q = blockIdx.x & 3;
  const int nb = g * NPG_;
  const int t = threadIdx.x;
  {
    const float4* src = reinterpret_cast<const float4*>(h1w + (size_t)nb * 16);
    float4* dst = reinterpret_cast<float4*>(hds);
    for (int i = t; i < NPG_ * 4; i += 1024) dst[i] = src[i];
  }
  __syncthreads();
  const int c = t & 15;
  const int vend = q * 400 + 400;
  for (int vl = q * 400 + (t >> 4); vl < vend; vl += 64) {
    const int v = nb + vl;
    if (!kept[v]) continue;                       // uniform per 16-group
    const int rs = offs[v], re = rend[v];
    float acc = 0.f;
    int k = rs;
    for (; k + 4 <= re; k += 4) {
      const int s0 = csr[k], s1 = csr[k + 1];
      const int s2 = csr[k + 2], s3 = csr[k + 3];
      acc += hds[s0 * 16 + c] + hds[s1 * 16 + c];
      acc += hds[s2 * 16 + c] + hds[s3 * 16 + c];
    }
    for (; k < re; ++k) acc += hds[csr[k] * 16 + c];
    acc += hds[vl * 16 + c];                      // self loop
    y16[(size_t)v * 16 + c] = acc * dis2[v];
  }
}

// ---------------------------------------------------------------------------
// K6: out[g] += relu(y16[v]@W2 + b2)/K  fused GEMM+ReLU+mean-pool.
// ---------------------------------------------------------------------------
__global__ __launch_bounds__(256, 1) void k_gemm2pool(const float* __restrict__ y16,
                                                      const int* __restrict__ kept,
                                                      const float* __restrict__ W2,
                                                      const float* __restrict__ b2,
                                                      float* __restrict__ out) {
  __shared__ float red[256];
  const int blk = blockIdx.x;                     // grid 2048
  const int g = blk >> 5;
  const int sub = blk & 31;
  const int jbase = (sub & 1) * 256;
  const int nstart = g * NPG_ + (sub >> 1) * 100;
  const int tid = threadIdx.x;
  const int wave = tid >> 6, lane = tid & 63;

  float w[16][4];
#pragma unroll
  for (int k = 0; k < 16; ++k)
#pragma unroll
    for (int c = 0; c < 4; ++c)
      w[k][c] = W2[k * HOUT_ + jbase + lane + c * 64];
  float b2r[4];
#pragma unroll
  for (int c = 0; c < 4; ++c) b2r[c] = b2[jbase + lane + c * 64];

  float acc[4] = {0.f, 0.f, 0.f, 0.f};
  for (int i = wave; i < 100; i += 4) {
    const int v = nstart + i;
    if (!kept[v]) continue;                       // wave-uniform
    const float4* yp = reinterpret_cast<const float4*>(y16 + (size_t)v * 16);
    float4 q0 = yp[0], q1 = yp[1], q2 = yp[2], q3 = yp[3];
    const float yv[16] = {q0.x, q0.y, q0.z, q0.w, q1.x, q1.y, q1.z, q1.w,
                          q2.x, q2.y, q2.z, q2.w, q3.x, q3.y, q3.z, q3.w};
    float z[4] = {b2r[0], b2r[1], b2r[2], b2r[3]};
#pragma unroll
    for (int k = 0; k < 16; ++k)
#pragma unroll
      for (int c = 0; c < 4; ++c)
        z[c] = fmaf(yv[k], w[k][c], z[c]);
#pragma unroll
    for (int c = 0; c < 4; ++c) acc[c] += fmaxf(z[c], 0.f);
  }

  red[tid] = 0.f;
  __syncthreads();
#pragma unroll
  for (int c = 0; c < 4; ++c) atomicAdd(&red[lane + 64 * c], acc[c]);
  __syncthreads();
  atomicAdd(&out[g * HOUT_ + jbase + tid], red[tid] * (1.0f / (float)KEEP_));
}

// ---------------------------------------------------------------------------
extern "C" void kernel_launch(void* const* d_in, const int* in_sizes, int n_in,
                              void* d_out, int out_size, void* d_ws, size_t ws_size,
                              hipStream_t stream) {
  (void)in_sizes; (void)n_in; (void)out_size; (void)ws_size;
  const float* x     = (const float*)d_in[0];
  const int*   ei    = (const int*)  d_in[1];
  const float* W1    = (const float*)d_in[3];
  const float* b1    = (const float*)d_in[4];
  const float* Wrel  = (const float*)d_in[5];
  const float* brel  = (const float*)d_in[6];
  const float* Wroot = (const float*)d_in[7];
  const float* W2    = (const float*)d_in[8];
  const float* b2    = (const float*)d_in[9];
  const int* esrc = ei;
  const int* edst = ei + E_;

  // slab quarters: hd / h1 / h1w / y16
  char* ws = (char*)d_ws;
  float*          hd    = (float*)(ws);                    // q0: 6,553,600 B
  float*          h1    = (float*)(ws + 6553600);          // q1
  float*          h1w   = (float*)(ws + 13107200);         // q2
  float*          y16   = (float*)(ws + 19660800);         // q3
  unsigned short* csr   = (unsigned short*)(ws + 26214400);// 6,553,600 B
  int*            offs  = (int*)(ws + 32768000);
  int*            rendp = (int*)(ws + 33177600);
  float*          dis   = (float*)(ws + 33587200);
  int*            kept  = (int*)(ws + 33996800);
  float*          rarr  = (float*)(ws + 34406400);
  float*          tarr  = (float*)(ws + 34816000);
  float*          dis2  = (float*)(ws + 35225600);
  float*          out   = (float*)d_out;

  hipLaunchKernelGGL(k_build,     dim3(G_),    dim3(1024), 0, stream,
                     esrc, edst, offs, rendp, dis, csr);
  hipLaunchKernelGGL(k_xw1,       dim3(800),   dim3(128),  0, stream,
                     x, W1, dis, hd);
  hipLaunchKernelGGL(k_conv1l,    dim3(256),   dim3(1024), 0, stream,
                     csr, offs, rendp, hd, dis, b1, Wrel, Wroot, h1, rarr, tarr);
  hipLaunchKernelGGL(k_scoretopk, dim3(G_),    dim3(1024), 0, stream,
                     csr, offs, rendp, rarr, tarr, brel, h1, kept, dis2, h1w, out);
  hipLaunchKernelGGL(k_conv2l,    dim3(256),   dim3(1024), 0, stream,
                     csr, offs, rendp, h1w, kept, dis2, y16);
  hipLaunchKernelGGL(k_gemm2pool, dim3(2048),  dim3(256),  0, stream,
                     y16, kept, W2, b2, out);
}

// Round 3
// 241.299 us; speedup vs baseline: 1.2986x; 1.0811x over previous
//
#include <hip/hip_runtime.h>
#include <math.h>

#define G_    64
#define NPG_  1600
#define N_    (G_*NPG_)     // 102400
#define EPG_  51200
#define E_    (G_*EPG_)     // 3276800
#define FIN_  512
#define HOUT_ 512
#define KEEP_ 1280

// ---------------------------------------------------------------------------
// K1: per-graph CSR build.  LDS degree hist -> shuffle scan -> LDS-cursor
// scatter INTO LDS (csrs), then coalesced uint4 copy-out.
// ---------------------------------------------------------------------------
__global__ __launch_bounds__(1024) void k_build(const int* __restrict__ esrc,
                                                const int* __restrict__ edst,
                                                int* __restrict__ offs,
                                                int* __restrict__ rend,
                                                float* __restrict__ dis,
                                                unsigned short* __restrict__ csr) {
  __shared__ __align__(16) unsigned short csrs[EPG_];   // 102,400 B
  __shared__ int hist[NPG_];                            // 6,400 B
  __shared__ int wsum[16];
  const int g = blockIdx.x, t = threadIdx.x;
  const int lane = t & 63, wid = t >> 6;
  const int eb = g * EPG_, nb = g * NPG_;

  for (int i = t; i < NPG_; i += 1024) hist[i] = 0;
  __syncthreads();
  for (int e = t; e < EPG_; e += 1024) atomicAdd(&hist[edst[eb + e] - nb], 1);
  __syncthreads();

  int c0 = 0, c1 = 0;
  if (t < 800) { c0 = hist[2 * t]; c1 = hist[2 * t + 1]; }
  const int val = c0 + c1;
  int incl = val;
#pragma unroll
  for (int m = 1; m < 64; m <<= 1) {
    const int u = __shfl_up(incl, m);
    if (lane >= m) incl += u;
  }
  if (lane == 63) wsum[wid] = incl;
  __syncthreads();
  int woff = 0;
  for (int w2 = 0; w2 < wid; ++w2) woff += wsum[w2];
  incl += woff;
  if (t < 800) {
    const int excl = incl - val;          // LOCAL edge offset
    const int p0 = excl, p1 = p0 + c0;
    offs[nb + 2 * t] = eb + p0;     rend[nb + 2 * t] = eb + p1;
    offs[nb + 2 * t + 1] = eb + p1; rend[nb + 2 * t + 1] = eb + p1 + c1;
    dis[nb + 2 * t] = rsqrtf((float)c0 + 1.0f);
    dis[nb + 2 * t + 1] = rsqrtf((float)c1 + 1.0f);
    hist[2 * t] = p0;          // reuse as LOCAL cursor
    hist[2 * t + 1] = p1;
  }
  __syncthreads();
  for (int e = t; e < EPG_; e += 1024) {
    const int s = esrc[eb + e];
    const int d = edst[eb + e] - nb;
    const int p = atomicAdd(&hist[d], 1);
    csrs[p] = (unsigned short)(s - nb);
  }
  __syncthreads();
  // coalesced copy-out: 6400 x uint4 (8 u16 each)
  const uint4* s4 = reinterpret_cast<const uint4*>(csrs);
  uint4* d4 = reinterpret_cast<uint4*>(csr + eb);
  for (int i = t; i < EPG_ / 8; i += 1024) d4[i] = s4[i];
}

// ---------------------------------------------------------------------------
// K2: hd[r] = (x[r] @ W1) * dis[r].
// W1 (32 KB) staged ONCE into LDS: per-k4 weight reads become same-address
// ds_read_b128 broadcasts (conflict-free, lgkmcnt-pipelined) instead of the
// serial 64-float SGPR s_load chain that stalled every previous version.
// x is read directly (per-lane row, 128 independent float4 loads -> deep
// ILP); no barriers in the main loop.  L2 absorbs the strided-line reuse
// (per-XCD working set ~1.3 MB << 4 MB), so HBM fetch stays ~x-size.
// ---------------------------------------------------------------------------
__global__ __launch_bounds__(128) void k_xw1(const float* __restrict__ x,
                                             const float* __restrict__ W1,
                                             const float* __restrict__ dis,
                                             float* __restrict__ hd) {
  __shared__ __align__(16) float wl[FIN_ * 16];   // 32,768 B
  const int t = threadIdx.x;
  {
    const float4* wg = reinterpret_cast<const float4*>(W1);
    float4* wd = reinterpret_cast<float4*>(wl);
    for (int i = t; i < FIN_ * 4; i += 128) wd[i] = wg[i];
  }
  __syncthreads();

  const int r = blockIdx.x * 128 + t;             // grid 800
  const float4* xr = reinterpret_cast<const float4*>(x + (size_t)r * FIN_);
  float acc[16];
#pragma unroll
  for (int j = 0; j < 16; ++j) acc[j] = 0.f;

#pragma unroll 2
  for (int k4 = 0; k4 < 128; ++k4) {
    const float4 xv = xr[k4];
    const float* w = wl + k4 * 64;                // LDS, same addr all lanes
#pragma unroll
    for (int j = 0; j < 16; ++j) acc[j] = fmaf(xv.x, w[j], acc[j]);
#pragma unroll
    for (int j = 0; j < 16; ++j) acc[j] = fmaf(xv.y, w[16 + j], acc[j]);
#pragma unroll
    for (int j = 0; j < 16; ++j) acc[j] = fmaf(xv.z, w[32 + j], acc[j]);
#pragma unroll
    for (int j = 0; j < 16; ++j) acc[j] = fmaf(xv.w, w[48 + j], acc[j]);
  }

  const float dd = dis[r];
  float4* pr = reinterpret_cast<float4*>(hd) + (size_t)r * 4;
  pr[0] = make_float4(acc[0] * dd, acc[1] * dd, acc[2] * dd, acc[3] * dd);
  pr[1] = make_float4(acc[4] * dd, acc[5] * dd, acc[6] * dd, acc[7] * dd);
  pr[2] = make_float4(acc[8] * dd, acc[9] * dd, acc[10] * dd, acc[11] * dd);
  pr[3] = make_float4(acc[12] * dd, acc[13] * dd, acc[14] * dd, acc[15] * dd);
}

// ---------------------------------------------------------------------------
// K3: conv1 gather, LDS-staged (per-graph hd slice = 102.4 KB in LDS).
// ---------------------------------------------------------------------------
__global__ __launch_bounds__(1024) void k_conv1l(
    const unsigned short* __restrict__ csr, const int* __restrict__ offs,
    const int* __restrict__ rend, const float* __restrict__ hd,
    const float* __restrict__ dis, const float* __restrict__ b1,
    const float* __restrict__ Wrel, const float* __restrict__ Wroot,
    float* __restrict__ h1, float* __restrict__ rarr, float* __restrict__ tarr) {
  __shared__ float hds[NPG_ * 16];                // 102,400 B
  const int g = blockIdx.x >> 2, q = blockIdx.x & 3;
  const int nb = g * NPG_;
  const int t = threadIdx.x;
  {
    const float4* src = reinterpret_cast<const float4*>(hd + (size_t)nb * 16);
    float4* dst = reinterpret_cast<float4*>(hds);
    for (int i = t; i < NPG_ * 4; i += 1024) dst[i] = src[i];
  }
  __syncthreads();
  const int c = t & 15;
  const float bb = b1[c], wr = Wrel[c], wo = Wroot[c];
  const int vend = q * 400 + 400;
  for (int vl = q * 400 + (t >> 4); vl < vend; vl += 64) {
    const int v = nb + vl;
    const int rs = offs[v], re = rend[v];
    float acc = 0.f;
    int k = rs;
    for (; k + 4 <= re; k += 4) {
      const int s0 = csr[k], s1 = csr[k + 1];
      const int s2 = csr[k + 2], s3 = csr[k + 3];
      acc += hds[s0 * 16 + c] + hds[s1 * 16 + c];
      acc += hds[s2 * 16 + c] + hds[s3 * 16 + c];
    }
    for (; k < re; ++k) acc += hds[csr[k] * 16 + c];
    const float dd = dis[v];
    float val = fmaf(acc + hds[vl * 16 + c], dd, bb);
    val = fmaxf(val, 0.f);
    h1[(size_t)v * 16 + c] = val;
    float r = val * wr;
    float tt = val * wo;
#pragma unroll
    for (int m = 1; m < 16; m <<= 1) {
      r += __shfl_xor(r, m);
      tt += __shfl_xor(tt, m);
    }
    if (c == 0) { rarr[v] = r; tarr[v] = tt; }
  }
}

// ---------------------------------------------------------------------------
// K4: per-graph fused score + radix-select top-K + filtered degree + h1w.
// Scans are shuffle-based.
// ---------------------------------------------------------------------------
__global__ __launch_bounds__(1024) void k_scoretopk(
    const unsigned short* __restrict__ csr, const int* __restrict__ offs,
    const int* __restrict__ rend, const float* __restrict__ rarr,
    const float* __restrict__ tarr, const float* __restrict__ brel,
    const float* __restrict__ h1, int* __restrict__ kept,
    float* __restrict__ dis2, float* __restrict__ h1w,
    float* __restrict__ out) {
  __shared__ float rar[NPG_];
  __shared__ float sar[NPG_];       // tarr, then score
  __shared__ int   ofs[NPG_];
  __shared__ int   ren[NPG_];
  __shared__ unsigned uu[NPG_];     // monotone keys
  __shared__ int   kp[NPG_];
  __shared__ float wv[NPG_];
  __shared__ int   hist[256];
  __shared__ int   part[16];        // per-wave scan sums
  __shared__ int   scal[2];         // lo, rem

  const int g = blockIdx.x, t = threadIdx.x;
  const int lane = t & 63, wid = t >> 6;
  const int nb = g * NPG_;

  // P0: stage
  for (int i = t; i < NPG_; i += 1024) {
    rar[i] = rarr[nb + i];
    sar[i] = tarr[nb + i];
    ofs[i] = offs[nb + i];
    ren[i] = rend[nb + i];
  }
  if (t == 0) { scal[0] = 0; scal[1] = KEEP_; }
  __syncthreads();

  // P1: score = tanh(sum rar[neighbors] + brel + tarr)
  const float br = brel[0];
  for (int v = t; v < NPG_; v += 1024) {
    const int rs = ofs[v], re = ren[v];
    float sum = 0.f;
    int k = rs;
    for (; k + 4 <= re; k += 4) {
      sum += rar[csr[k]] + rar[csr[k + 1]];
      sum += rar[csr[k + 2]] + rar[csr[k + 3]];
    }
    for (; k < re; ++k) sum += rar[csr[k]];
    const float s = tanhf(sum + br + sar[v]);
    sar[v] = s;
    const unsigned ub = __float_as_uint(s);
    uu[v] = (ub & 0x80000000u) ? ~ub : (ub | 0x80000000u);
  }
  __syncthreads();

  // P2: radix select (4 passes of 8 bits, MSB first)
  const unsigned maskTab[4] = {0u, 0xFF000000u, 0xFFFF0000u, 0xFFFFFF00u};
  const int shTab[4] = {24, 16, 8, 0};
  for (int pass = 0; pass < 4; ++pass) {
    const unsigned lo = (unsigned)scal[0];
    const int remc = scal[1];
    const unsigned msk = maskTab[pass];
    const int sh = shTab[pass];
    if (t < 256) hist[t] = 0;
    __syncthreads();
    for (int v = t; v < NPG_; v += 1024) {
      const unsigned u = uu[v];
      if (((u ^ lo) & msk) == 0) atomicAdd(&hist[(u >> sh) & 255], 1);
    }
    __syncthreads();
    int hv = 0;
    if (t < 256) hv = hist[t];
    int incl = hv;
#pragma unroll
    for (int m = 1; m < 64; m <<= 1) {
      const int u2 = __shfl_up(incl, m);
      if (lane >= m) incl += u2;
    }
    if (t < 256 && lane == 63) part[wid] = incl;  // waves 0..3
    __syncthreads();
    if (t < 256) {
      int woff = 0;
      for (int w2 = 0; w2 < wid; ++w2) woff += part[w2];
      const int tot = part[0] + part[1] + part[2] + part[3];
      const int sb = tot - (incl + woff) + hv;    // suffix sum from bin t
      const int sb1 = sb - hv;                    // suffix sum from bin t+1
      if (sb >= remc && sb1 < remc) {             // unique boundary bin
        scal[0] = (int)(lo | ((unsigned)t << sh));
        scal[1] = remc - sb1;
      }
    }
    __syncthreads();
  }
  const unsigned T = (unsigned)scal[0];
  const int remT = scal[1];

  // tie-break by index: keep first remT nodes with key == T (shuffle scan)
  const int i0 = 2 * t, i1 = 2 * t + 1;
  int f0 = 0, f1 = 0;
  if (i0 < NPG_) f0 = (uu[i0] == T);
  if (i1 < NPG_) f1 = (uu[i1] == T);
  int incl2 = f0 + f1;
#pragma unroll
  for (int m = 1; m < 64; m <<= 1) {
    const int u2 = __shfl_up(incl2, m);
    if (lane >= m) incl2 += u2;
  }
  if (lane == 63) part[wid] = incl2;
  __syncthreads();
  int woff2 = 0;
  for (int w2 = 0; w2 < wid; ++w2) woff2 += part[w2];
  const int excl = incl2 + woff2 - (f0 + f1);
  if (i0 < NPG_) kp[i0] = (uu[i0] > T) || (f0 && excl < remT);
  if (i1 < NPG_) kp[i1] = (uu[i1] > T) || (f1 && (excl + f0) < remT);
  __syncthreads();
  for (int v = t; v < NPG_; v += 1024) kept[nb + v] = kp[v];

  // P3: filtered degree -> dis2, wv = score * dis2 (0 for dropped)
  for (int v = t; v < NPG_; v += 1024) {
    float w = 0.f;
    if (kp[v]) {
      const int rs = ofs[v], re = ren[v];
      int c2 = 0, k = rs;
      for (; k + 4 <= re; k += 4) {
        c2 += kp[csr[k]] + kp[csr[k + 1]];
        c2 += kp[csr[k + 2]] + kp[csr[k + 3]];
      }
      for (; k < re; ++k) c2 += kp[csr[k]];
      const float d2 = rsqrtf((float)c2 + 1.0f);
      dis2[nb + v] = d2;
      w = sar[v] * d2;
    }
    wv[v] = w;
  }
  // zero the output slice for this graph
  if (t < HOUT_) out[g * HOUT_ + t] = 0.f;
  __syncthreads();

  // P4: h1w = h1 * wv[v]
  for (int i = t; i < NPG_ * 16; i += 1024)
    h1w[(size_t)nb * 16 + i] = h1[(size_t)nb * 16 + i] * wv[i >> 4];
}

// ---------------------------------------------------------------------------
// K5: conv2 gather, LDS-staged (same structure as K3).
// ---------------------------------------------------------------------------
__global__ __launch_bounds__(1024) void k_conv2l(
    const unsigned short* __restrict__ csr, const int* __restrict__ offs,
    const int* __restrict__ rend, const float* __restrict__ h1w,
    const int* __restrict__ kept, const float* __restrict__ dis2,
    float* __restrict__ y16) {
  __shared__ float hds[NPG_ * 16];                // 102,400 B
  const int g = blockIdx.x >> 2, q = blockIdx.x & 3;
  const int nb = g * NPG_;
  const int t = threadIdx.x;
  {
    const float4* src = reinterpret_cast<const float4*>(h1w + (size_t)nb * 16);
    float4* dst = reinterpret_cast<float4*>(hds);
    for (int i = t; i < NPG_ * 4; i += 1024) dst[i] = src[i];
  }
  __syncthreads();
  const int c = t & 15;
  const int vend = q * 400 + 400;
  for (int vl = q * 400 + (t >> 4); vl < vend; vl += 64) {
    const int v = nb + vl;
    if (!kept[v]) continue;                       // uniform per 16-group
    const int rs = offs[v], re = rend[v];
    float acc = 0.f;
    int k = rs;
    for (; k + 4 <= re; k += 4) {
      const int s0 = csr[k], s1 = csr[k + 1];
      const int s2 = csr[k + 2], s3 = csr[k + 3];
      acc += hds[s0 * 16 + c] + hds[s1 * 16 + c];
      acc += hds[s2 * 16 + c] + hds[s3 * 16 + c];
    }
    for (; k < re; ++k) acc += hds[csr[k] * 16 + c];
    acc += hds[vl * 16 + c];                      // self loop
    y16[(size_t)v * 16 + c] = acc * dis2[v];
  }
}

// ---------------------------------------------------------------------------
// K6: out[g] += relu(y16[v]@W2 + b2)/K  fused GEMM+ReLU+mean-pool.
// ---------------------------------------------------------------------------
__global__ __launch_bounds__(256, 1) void k_gemm2pool(const float* __restrict__ y16,
                                                      const int* __restrict__ kept,
                                                      const float* __restrict__ W2,
                                                      const float* __restrict__ b2,
                                                      float* __restrict__ out) {
  __shared__ float red[256];
  const int blk = blockIdx.x;                     // grid 2048
  const int g = blk >> 5;
  const int sub = blk & 31;
  const int jbase = (sub & 1) * 256;
  const int nstart = g * NPG_ + (sub >> 1) * 100;
  const int tid = threadIdx.x;
  const int wave = tid >> 6, lane = tid & 63;

  float w[16][4];
#pragma unroll
  for (int k = 0; k < 16; ++k)
#pragma unroll
    for (int c = 0; c < 4; ++c)
      w[k][c] = W2[k * HOUT_ + jbase + lane + c * 64];
  float b2r[4];
#pragma unroll
  for (int c = 0; c < 4; ++c) b2r[c] = b2[jbase + lane + c * 64];

  float acc[4] = {0.f, 0.f, 0.f, 0.f};
  for (int i = wave; i < 100; i += 4) {
    const int v = nstart + i;
    if (!kept[v]) continue;                       // wave-uniform
    const float4* yp = reinterpret_cast<const float4*>(y16 + (size_t)v * 16);
    float4 q0 = yp[0], q1 = yp[1], q2 = yp[2], q3 = yp[3];
    const float yv[16] = {q0.x, q0.y, q0.z, q0.w, q1.x, q1.y, q1.z, q1.w,
                          q2.x, q2.y, q2.z, q2.w, q3.x, q3.y, q3.z, q3.w};
    float z[4] = {b2r[0], b2r[1], b2r[2], b2r[3]};
#pragma unroll
    for (int k = 0; k < 16; ++k)
#pragma unroll
      for (int c = 0; c < 4; ++c)
        z[c] = fmaf(yv[k], w[k][c], z[c]);
#pragma unroll
    for (int c = 0; c < 4; ++c) acc[c] += fmaxf(z[c], 0.f);
  }

  red[tid] = 0.f;
  __syncthreads();
#pragma unroll
  for (int c = 0; c < 4; ++c) atomicAdd(&red[lane + 64 * c], acc[c]);
  __syncthreads();
  atomicAdd(&out[g * HOUT_ + jbase + tid], red[tid] * (1.0f / (float)KEEP_));
}

// ---------------------------------------------------------------------------
extern "C" void kernel_launch(void* const* d_in, const int* in_sizes, int n_in,
                              void* d_out, int out_size, void* d_ws, size_t ws_size,
                              hipStream_t stream) {
  (void)in_sizes; (void)n_in; (void)out_size; (void)ws_size;
  const float* x     = (const float*)d_in[0];
  const int*   ei    = (const int*)  d_in[1];
  const float* W1    = (const float*)d_in[3];
  const float* b1    = (const float*)d_in[4];
  const float* Wrel  = (const float*)d_in[5];
  const float* brel  = (const float*)d_in[6];
  const float* Wroot = (const float*)d_in[7];
  const float* W2    = (const float*)d_in[8];
  const float* b2    = (const float*)d_in[9];
  const int* esrc = ei;
  const int* edst = ei + E_;

  // slab quarters: hd / h1 / h1w / y16
  char* ws = (char*)d_ws;
  float*          hd    = (float*)(ws);                    // q0: 6,553,600 B
  float*          h1    = (float*)(ws + 6553600);          // q1
  float*          h1w   = (float*)(ws + 13107200);         // q2
  float*          y16   = (float*)(ws + 19660800);         // q3
  unsigned short* csr   = (unsigned short*)(ws + 26214400);// 6,553,600 B
  int*            offs  = (int*)(ws + 32768000);
  int*            rendp = (int*)(ws + 33177600);
  float*          dis   = (float*)(ws + 33587200);
  int*            kept  = (int*)(ws + 33996800);
  float*          rarr  = (float*)(ws + 34406400);
  float*          tarr  = (float*)(ws + 34816000);
  float*          dis2  = (float*)(ws + 35225600);
  float*          out   = (float*)d_out;

  hipLaunchKernelGGL(k_build,     dim3(G_),    dim3(1024), 0, stream,
                     esrc, edst, offs, rendp, dis, csr);
  hipLaunchKernelGGL(k_xw1,       dim3(800),   dim3(128),  0, stream,
                     x, W1, dis, hd);
  hipLaunchKernelGGL(k_conv1l,    dim3(256),   dim3(1024), 0, stream,
                     csr, offs, rendp, hd, dis, b1, Wrel, Wroot, h1, rarr, tarr);
  hipLaunchKernelGGL(k_scoretopk, dim3(G_),    dim3(1024), 0, stream,
                     csr, offs, rendp, rarr, tarr, brel, h1, kept, dis2, h1w, out);
  hipLaunchKernelGGL(k_conv2l,    dim3(256),   dim3(1024), 0, stream,
                     csr, offs, rendp, h1w, kept, dis2, y16);
  hipLaunchKernelGGL(k_gemm2pool, dim3(2048),  dim3(256),  0, stream,
                     y16, kept, W2, b2, out);
}